// Round 3
// baseline (205.368 us; speedup 1.0000x reference)
//
#include <hip/hip_runtime.h>
#include <hip/hip_bf16.h>
#include <math.h>

#define NN 8192
#define KK 128
#define DD 128

typedef short bf16x8 __attribute__((ext_vector_type(8)));
typedef float f32x4 __attribute__((ext_vector_type(4)));

static __device__ __forceinline__ short f2bf(float f) {
    __hip_bfloat16 h = __float2bfloat16(f);
    return __builtin_bit_cast(short, h);
}

// ---------------- prep_k: M_k (bf16), b_k = M_k*mean_k, c_k = logdet + logsoftmax(w)_k
// grid (KK, 4), 256 threads. Block (k, slice) builds rows [slice*32, slice*32+32).
__global__ __launch_bounds__(256) void prep_k(const float* __restrict__ means,
                                              const float* __restrict__ logvar,
                                              const float* __restrict__ tri,
                                              const float* __restrict__ weigh,
                                              __hip_bfloat16* __restrict__ Mb,
                                              float* __restrict__ bvec,
                                              float* __restrict__ cvec) {
    int k = blockIdx.x, slice = blockIdx.y;
    int t = threadIdx.x;
    __shared__ float svar[DD], smean[DD], red[DD];
    if (t < DD) {
        float var = expf(tanhf(logvar[k * DD + t]));
        svar[t]  = var;
        smean[t] = means[k * DD + t];
        red[t]   = logf(var + 1e-8f);
    }
    __syncthreads();

    int w = t >> 6, lane = t & 63;
    const float* trik = tri + (size_t)k * DD * DD;
    __hip_bfloat16* Mk = Mb + (size_t)k * DD * DD;
#pragma unroll
    for (int rr = 0; rr < 8; rr++) {
        int i = slice * 32 + w * 8 + rr;
        int j0 = lane, j1 = lane + 64;
        float m0 = (j0 < i) ? trik[i * DD + j0] * svar[j0] : ((j0 == i) ? svar[j0] : 0.f);
        float m1 = (j1 < i) ? trik[i * DD + j1] * svar[j1] : ((j1 == i) ? svar[j1] : 0.f);
        Mk[i * DD + j0] = __float2bfloat16(m0);
        Mk[i * DD + j1] = __float2bfloat16(m1);
        float b = m0 * smean[j0] + m1 * smean[j1];
#pragma unroll
        for (int off = 32; off; off >>= 1) b += __shfl_xor(b, off, 64);
        if (lane == 0) bvec[k * DD + i] = b;
    }

    __syncthreads();
    if (slice == 0 && t < 64) {
        float ld = red[t] + red[t + 64];
#pragma unroll
        for (int off = 32; off; off >>= 1) ld += __shfl_xor(ld, off, 64);
        float w0 = weigh[t], w1 = weigh[t + 64];
        float mx = fmaxf(w0, w1);
#pragma unroll
        for (int off = 32; off; off >>= 1) mx = fmaxf(mx, __shfl_xor(mx, off, 64));
        float e = expf(w0 - mx) + expf(w1 - mx);
#pragma unroll
        for (int off = 32; off; off >>= 1) e += __shfl_xor(e, off, 64);
        if (t == 0) cvec[k] = ld + weigh[k] - (mx + logf(e));
    }
}

// ---------------- gemm_q: streaming GEMM + q + running-logsumexp epilogue.
// grid (NN/128, KK/8), 256 threads = 4 waves. Wave w owns rows n0+w*32..+31 (rt<2).
// A in registers (f32->bf16 in-kernel); B fragments stream global->VGPR with
// one-step ping-pong prefetch. Per block: 8 k's; emits per-row (m,s) LSE partials.
__global__ __launch_bounds__(256, 2) void gemm_q(const float* __restrict__ X,
                                                 const __hip_bfloat16* __restrict__ Mb,
                                                 const float* __restrict__ bvec,
                                                 const float* __restrict__ cvec,
                                                 float* __restrict__ pm,
                                                 float* __restrict__ ps) {
    int tid  = threadIdx.x;
    int w    = tid >> 6, lane = tid & 63;
    int quad = lane >> 4, l15 = lane & 15;
    int n0 = blockIdx.x * 128;
    int k0 = blockIdx.y * 8;
    int kg = blockIdx.y;

    // A fragments: af[rt][s] covers row n0+w*32+rt*16+l15, k-elems s*32+quad*8..+8
    bf16x8 af[2][4];
#pragma unroll
    for (int rt = 0; rt < 2; rt++) {
        const float* xr = X + (size_t)(n0 + w * 32 + rt * 16 + l15) * DD;
#pragma unroll
        for (int s = 0; s < 4; s++) {
            const float* p = xr + s * 32 + quad * 8;
            float4 x0 = *(const float4*)(p);
            float4 x1 = *(const float4*)(p + 4);
            bf16x8 a;
            a[0] = f2bf(x0.x); a[1] = f2bf(x0.y); a[2] = f2bf(x0.z); a[3] = f2bf(x0.w);
            a[4] = f2bf(x1.x); a[5] = f2bf(x1.y); a[6] = f2bf(x1.z); a[7] = f2bf(x1.w);
            af[rt][s] = a;
        }
    }

    // running LSE state per row (valid identically on all 16 lanes of a quad-group)
    float rm[2][4], rsum[2][4];
#pragma unroll
    for (int rt = 0; rt < 2; rt++)
#pragma unroll
        for (int r = 0; r < 4; r++) { rm[rt][r] = -INFINITY; rsum[rt][r] = 0.f; }

    const char* Bk0 = (const char*)Mb + (size_t)k0 * (DD * DD * 2);

    // ping-pong B fragment buffers; parity of flat step (kk*4+s)
    bf16x8 frag[2][8];
#pragma unroll
    for (int ct = 0; ct < 8; ct++)
        frag[0][ct] = *(const bf16x8*)(Bk0 + (ct * 16 + l15) * 256 + quad * 16);

#pragma unroll 1
    for (int kk = 0; kk < 8; kk++) {
        const char* Bk = Bk0 + kk * 32768;
        float ck = cvec[k0 + kk];
        float bb[8];
#pragma unroll
        for (int ct = 0; ct < 8; ct++) bb[ct] = bvec[(k0 + kk) * DD + ct * 16 + l15];

        f32x4 acc[2][8];
#pragma unroll
        for (int rt = 0; rt < 2; rt++)
#pragma unroll
            for (int ct = 0; ct < 8; ct++) acc[rt][ct] = (f32x4){0.f, 0.f, 0.f, 0.f};

#pragma unroll
        for (int s = 0; s < 4; s++) {
            int p = s & 1, np = p ^ 1;
            // prefetch step kk*4+s+1
            int ns = s + 1, nkk = kk;
            if (ns == 4) { ns = 0; nkk = kk + 1; }
            if (nkk < 8) {
                const char* Bn = Bk0 + nkk * 32768;
#pragma unroll
                for (int ct = 0; ct < 8; ct++)
                    frag[np][ct] = *(const bf16x8*)(Bn + (ct * 16 + l15) * 256 + ns * 64 + quad * 16);
            }
#pragma unroll
            for (int ct = 0; ct < 8; ct++)
#pragma unroll
                for (int rt = 0; rt < 2; rt++)
                    acc[rt][ct] = __builtin_amdgcn_mfma_f32_16x16x32_bf16(af[rt][s], frag[p][ct], acc[rt][ct], 0, 0, 0);
        }

        // epilogue for this k: q = sum_col (Z-b)^2 ; logit = -q/2 + ck ; fold into LSE
#pragma unroll
        for (int rt = 0; rt < 2; rt++) {
            float rs[4] = {0.f, 0.f, 0.f, 0.f};
#pragma unroll
            for (int ct = 0; ct < 8; ct++) {
                float bbv = bb[ct];
#pragma unroll
                for (int r = 0; r < 4; r++) {
                    float z = acc[rt][ct][r] - bbv;
                    rs[r] = fmaf(z, z, rs[r]);
                }
            }
#pragma unroll
            for (int r = 0; r < 4; r++) {
#pragma unroll
                for (int off = 1; off < 16; off <<= 1)
                    rs[r] += __shfl_xor(rs[r], off, 64);
                float v = fmaf(rs[r], -0.5f, ck);
                float nm = fmaxf(rm[rt][r], v);
                rsum[rt][r] = rsum[rt][r] * __expf(rm[rt][r] - nm) + __expf(v - nm);
                rm[rt][r] = nm;
            }
        }
    }

    // store per-row LSE partials for this k-group (l15==0 lanes own rows quad*4..+3)
    if (l15 == 0) {
#pragma unroll
        for (int rt = 0; rt < 2; rt++) {
            int row0 = n0 + w * 32 + rt * 16 + quad * 4;
            float4 mo = { rm[rt][0], rm[rt][1], rm[rt][2], rm[rt][3] };
            float4 so = { rsum[rt][0], rsum[rt][1], rsum[rt][2], rsum[rt][3] };
            *(float4*)(pm + (size_t)kg * NN + row0) = mo;
            *(float4*)(ps + (size_t)kg * NN + row0) = so;
        }
    }
}

// ---------------- finalize: merge 16 LSE partials per n, mean. 32 blocks x 256.
__global__ __launch_bounds__(256) void finalize(const float* __restrict__ pm,
                                                const float* __restrict__ ps,
                                                float* __restrict__ out) {
    __shared__ float sred[256];
    int t = threadIdx.x;
    int n = blockIdx.x * 256 + t;
    float M = -INFINITY, S = 0.f;
#pragma unroll
    for (int g = 0; g < 16; g++) {
        float m = pm[(size_t)g * NN + n];
        float s = ps[(size_t)g * NN + n];
        float nm = fmaxf(M, m);
        S = S * expf(M - nm) + s * expf(m - nm);
        M = nm;
    }
    float lse = M + logf(S);
    const float logC = -64.f * 1.8378770664093453f;
    sred[t] = (-logC - lse) * (1.f / (float)NN);
    __syncthreads();
    for (int off = 128; off > 0; off >>= 1) { if (t < off) sred[t] += sred[t + off]; __syncthreads(); }
    if (t == 0) atomicAdd(out, sred[0]);
}

extern "C" void kernel_launch(void* const* d_in, const int* in_sizes, int n_in,
                              void* d_out, int out_size, void* d_ws, size_t ws_size,
                              hipStream_t stream) {
    const float* X      = (const float*)d_in[0];
    const float* means  = (const float*)d_in[1];
    const float* logvar = (const float*)d_in[2];
    const float* tri    = (const float*)d_in[3];
    const float* weigh  = (const float*)d_in[4];
    float* out = (float*)d_out;

    char* ws = (char*)d_ws;
    __hip_bfloat16* Mb   = (__hip_bfloat16*)(ws);          // 4 MiB
    float*          bvec = (float*)(ws + 4194304);         // 64 KiB
    float*          cvec = (float*)(ws + 4259840);         // 512 B
    float*          pm   = (float*)(ws + 4325376);         // 512 KiB (16 x 8192)
    float*          ps   = (float*)(ws + 4849664);         // 512 KiB

    hipMemsetAsync(d_out, 0, sizeof(float), stream);

    prep_k<<<dim3(KK, 4), 256, 0, stream>>>(means, logvar, tri, weigh, Mb, bvec, cvec);
    gemm_q<<<dim3(NN / 128, KK / 8), 256, 0, stream>>>(X, Mb, bvec, cvec, pm, ps);
    finalize<<<NN / 256, 256, 0, stream>>>(pm, ps, out);
}

// Round 4
// 127.037 us; speedup vs baseline: 1.6166x; 1.6166x over previous
//
#include <hip/hip_runtime.h>
#include <hip/hip_bf16.h>
#include <math.h>

#define NN 8192
#define KK 128
#define DD 128

typedef short bf16x8 __attribute__((ext_vector_type(8)));
typedef float f32x4 __attribute__((ext_vector_type(4)));
typedef __attribute__((address_space(3))) uint32_t lds_u32;
typedef const __attribute__((address_space(1))) uint32_t glb_u32;

static __device__ __forceinline__ short f2bf(float f) {
    __hip_bfloat16 h = __float2bfloat16(f);
    return __builtin_bit_cast(short, h);
}

// ---------------- prep_k: M_k (bf16), nbvec = -(M_k*mean_k), cvec = logdet + logsoftmax(w)_k
// grid (KK, 4), 256 threads. Block (k, slice) builds rows [slice*32, slice*32+32).
// Block (0,0) also zeroes d_out (runs before finalize on the stream).
__global__ __launch_bounds__(256) void prep_k(const float* __restrict__ means,
                                              const float* __restrict__ logvar,
                                              const float* __restrict__ tri,
                                              const float* __restrict__ weigh,
                                              __hip_bfloat16* __restrict__ Mb,
                                              float* __restrict__ nbvec,
                                              float* __restrict__ cvec,
                                              float* __restrict__ out) {
    int k = blockIdx.x, slice = blockIdx.y;
    int t = threadIdx.x;
    if (k == 0 && slice == 0 && t == 0) out[0] = 0.f;
    __shared__ float svar[DD], smean[DD], red[DD];
    if (t < DD) {
        float var = expf(tanhf(logvar[k * DD + t]));
        svar[t]  = var;
        smean[t] = means[k * DD + t];
        red[t]   = logf(var + 1e-8f);
    }
    __syncthreads();

    int w = t >> 6, lane = t & 63;
    const float* trik = tri + (size_t)k * DD * DD;
    __hip_bfloat16* Mk = Mb + (size_t)k * DD * DD;
#pragma unroll
    for (int rr = 0; rr < 8; rr++) {
        int i = slice * 32 + w * 8 + rr;
        int j0 = lane, j1 = lane + 64;
        float m0 = (j0 < i) ? trik[i * DD + j0] * svar[j0] : ((j0 == i) ? svar[j0] : 0.f);
        float m1 = (j1 < i) ? trik[i * DD + j1] * svar[j1] : ((j1 == i) ? svar[j1] : 0.f);
        Mk[i * DD + j0] = __float2bfloat16(m0);
        Mk[i * DD + j1] = __float2bfloat16(m1);
        float b = m0 * smean[j0] + m1 * smean[j1];
#pragma unroll
        for (int off = 32; off; off >>= 1) b += __shfl_xor(b, off, 64);
        if (lane == 0) nbvec[k * DD + i] = -b;
    }

    __syncthreads();
    if (slice == 0 && t < 64) {
        float ld = red[t] + red[t + 64];
#pragma unroll
        for (int off = 32; off; off >>= 1) ld += __shfl_xor(ld, off, 64);
        float w0 = weigh[t], w1 = weigh[t + 64];
        float mx = fmaxf(w0, w1);
#pragma unroll
        for (int off = 32; off; off >>= 1) mx = fmaxf(mx, __shfl_xor(mx, off, 64));
        float e = expf(w0 - mx) + expf(w1 - mx);
#pragma unroll
        for (int off = 32; off; off >>= 1) e += __shfl_xor(e, off, 64);
        if (t == 0) cvec[k] = ld + weigh[k] - (mx + logf(e));
    }
}

// ---------------- gemm_q: LDS-multicast B (M_k), X in registers, swapped operands.
// grid (NN/256, KK/8), 256 thr. acc[mt][nt]: m = z-col = mt*16+quad*4+r, n = x-row = nt*16+l15.
// M_k staged 32KB/k into 64KB LDS double buffer via global_load_lds (XOR-swizzled rows).
__global__ __launch_bounds__(256, 2) void gemm_q(const float* __restrict__ X,
                                                 const __hip_bfloat16* __restrict__ Mb,
                                                 const float* __restrict__ nbvec,
                                                 const float* __restrict__ cvec,
                                                 float* __restrict__ pm,
                                                 float* __restrict__ ps) {
    __shared__ char smem[65536];
    int tid  = threadIdx.x;
    int w    = tid >> 6, lane = tid & 63;
    int quad = lane >> 4, l15 = lane & 15;
    int n0 = blockIdx.x * 256;
    int kg = blockIdx.y, k0 = kg * 8;

    // X fragments (B-operand): Xf[nt][s] : lane l15 = x-row, quad*8+j = d-offset
    bf16x8 Xf[4][4];
#pragma unroll
    for (int nt = 0; nt < 4; nt++) {
        const float* xr = X + (size_t)(n0 + w * 64 + nt * 16 + l15) * DD;
#pragma unroll
        for (int s = 0; s < 4; s++) {
            const float* p = xr + s * 32 + quad * 8;
            float4 x0 = *(const float4*)(p);
            float4 x1 = *(const float4*)(p + 4);
            bf16x8 a;
            a[0] = f2bf(x0.x); a[1] = f2bf(x0.y); a[2] = f2bf(x0.z); a[3] = f2bf(x0.w);
            a[4] = f2bf(x1.x); a[5] = f2bf(x1.y); a[6] = f2bf(x1.z); a[7] = f2bf(x1.w);
            Xf[nt][s] = a;
        }
    }

    // stage M_{k0+kk} (32 KB) into LDS buffer `par` (0/1), XOR-swizzled:
    // LDS[row][c] = G[row][c ^ (row&15)] (16B chunks). Wave w stages rows w*32..+31.
    int rlo = lane >> 4, cl = lane & 15;
    auto stage = [&](int kk, int par) {
        const char* gk = (const char*)Mb + ((size_t)(k0 + kk) << 15);
#pragma unroll
        for (int i = 0; i < 8; i++) {
            int row = w * 32 + i * 4 + rlo;
            int gch = cl ^ (row & 15);
            const char* g = gk + row * 256 + gch * 16;
            char* lp = smem + par * 32768 + w * 8192 + i * 1024;
            __builtin_amdgcn_global_load_lds((glb_u32*)g, (lds_u32*)lp, 16, 0, 0);
        }
    };

    stage(0, 0);

    // swizzled read bases: A-frag (M) at row mt*16+l15, d-chunk s*4+quad
    const char* rbs[4];
#pragma unroll
    for (int s = 0; s < 4; s++)
        rbs[s] = smem + l15 * 256 + (((s * 4 + quad) ^ l15) << 4);

    float rm[4], rs[4];
#pragma unroll
    for (int nt = 0; nt < 4; nt++) { rm[nt] = -INFINITY; rs[nt] = 0.f; }

    __syncthreads();

#pragma unroll 1
    for (int kk = 0; kk < 8; kk++) {
        int par = (kk & 1) * 32768;
        if (kk < 7) stage(kk + 1, (kk + 1) & 1);

        int k = k0 + kk;
        // acc init = -b[m] (so acc ends as z = Mx - b)
        f32x4 acc[8][4];
#pragma unroll
        for (int mt = 0; mt < 8; mt++) {
            f32x4 b4 = *(const f32x4*)(nbvec + (k << 7) + mt * 16 + quad * 4);
#pragma unroll
            for (int nt = 0; nt < 4; nt++) acc[mt][nt] = b4;
        }

#pragma unroll
        for (int s = 0; s < 4; s++) {
#pragma unroll
            for (int mt = 0; mt < 8; mt++) {
                bf16x8 Af = *(const bf16x8*)(rbs[s] + par + mt * 4096);
#pragma unroll
                for (int nt = 0; nt < 4; nt++)
                    acc[mt][nt] = __builtin_amdgcn_mfma_f32_16x16x32_bf16(Af, Xf[nt][s], acc[mt][nt], 0, 0, 0);
            }
        }

        float ck = cvec[k];
        // q[n] = sum_m z^2 : per-lane over (mt,r), then reduce across quad (lane bits 4,5)
#pragma unroll
        for (int nt = 0; nt < 4; nt++) {
            float q = 0.f;
#pragma unroll
            for (int mt = 0; mt < 8; mt++) {
#pragma unroll
                for (int r = 0; r < 4; r++) {
                    float z = acc[mt][nt][r];
                    q = fmaf(z, z, q);
                }
            }
            q += __shfl_xor(q, 16, 64);
            q += __shfl_xor(q, 32, 64);
            float v = fmaf(q, -0.5f, ck);
            float nm = fmaxf(rm[nt], v);
            rs[nt] = rs[nt] * __expf(rm[nt] - nm) + __expf(v - nm);
            rm[nt] = nm;
        }

        if (kk < 7) __syncthreads();
    }

    // store per-row LSE partials for this k-group
    if (lane < 16) {
#pragma unroll
        for (int nt = 0; nt < 4; nt++) {
            int idx = kg * NN + n0 + w * 64 + nt * 16 + lane;
            pm[idx] = rm[nt];
            ps[idx] = rs[nt];
        }
    }
}

// ---------------- finalize: merge 16 LSE partials per n, mean. 32 blocks x 256.
__global__ __launch_bounds__(256) void finalize(const float* __restrict__ pm,
                                                const float* __restrict__ ps,
                                                float* __restrict__ out) {
    __shared__ float sred[256];
    int t = threadIdx.x;
    int n = blockIdx.x * 256 + t;
    float M = -INFINITY, S = 0.f;
#pragma unroll
    for (int g = 0; g < 16; g++) {
        float m = pm[(size_t)g * NN + n];
        float s = ps[(size_t)g * NN + n];
        float nm = fmaxf(M, m);
        S = S * expf(M - nm) + s * expf(m - nm);
        M = nm;
    }
    float lse = M + logf(S);
    const float logC = -64.f * 1.8378770664093453f;
    sred[t] = (-logC - lse) * (1.f / (float)NN);
    __syncthreads();
    for (int off = 128; off > 0; off >>= 1) { if (t < off) sred[t] += sred[t + off]; __syncthreads(); }
    if (t == 0) atomicAdd(out, sred[0]);
}

extern "C" void kernel_launch(void* const* d_in, const int* in_sizes, int n_in,
                              void* d_out, int out_size, void* d_ws, size_t ws_size,
                              hipStream_t stream) {
    const float* X      = (const float*)d_in[0];
    const float* means  = (const float*)d_in[1];
    const float* logvar = (const float*)d_in[2];
    const float* tri    = (const float*)d_in[3];
    const float* weigh  = (const float*)d_in[4];
    float* out = (float*)d_out;

    char* ws = (char*)d_ws;
    __hip_bfloat16* Mb    = (__hip_bfloat16*)(ws);          // 4 MiB
    float*          nbvec = (float*)(ws + 4194304);         // 64 KiB
    float*          cvec  = (float*)(ws + 4259840);         // 512 B
    float*          pm    = (float*)(ws + 4325376);         // 512 KiB (16 x 8192)
    float*          ps    = (float*)(ws + 4849664);         // 512 KiB

    prep_k<<<dim3(KK, 4), 256, 0, stream>>>(means, logvar, tri, weigh, Mb, nbvec, cvec, out);
    gemm_q<<<dim3(NN / 256, KK / 8), 256, 0, stream>>>(X, Mb, nbvec, cvec, pm, ps);
    finalize<<<NN / 256, 256, 0, stream>>>(pm, ps, out);
}

// Round 5
// 117.799 us; speedup vs baseline: 1.7434x; 1.0784x over previous
//
#include <hip/hip_runtime.h>
#include <hip/hip_bf16.h>
#include <math.h>

#define NN 8192
#define KK 128
#define DD 128

typedef short bf16x8 __attribute__((ext_vector_type(8)));
typedef float f32x4 __attribute__((ext_vector_type(4)));
typedef __attribute__((address_space(3))) uint32_t lds_u32;
typedef const __attribute__((address_space(1))) uint32_t glb_u32;

static __device__ __forceinline__ short f2bf(float f) {
    __hip_bfloat16 h = __float2bfloat16(f);
    return __builtin_bit_cast(short, h);
}

// ---------------- prep_k: M_k (bf16), nbvec = -(M_k*mean_k), cvec = logdet + logsoftmax(w)_k
__global__ __launch_bounds__(256) void prep_k(const float* __restrict__ means,
                                              const float* __restrict__ logvar,
                                              const float* __restrict__ tri,
                                              const float* __restrict__ weigh,
                                              __hip_bfloat16* __restrict__ Mb,
                                              float* __restrict__ nbvec,
                                              float* __restrict__ cvec,
                                              float* __restrict__ out) {
    int k = blockIdx.x, slice = blockIdx.y;
    int t = threadIdx.x;
    if (k == 0 && slice == 0 && t == 0) out[0] = 0.f;
    __shared__ float svar[DD], smean[DD], red[DD];
    if (t < DD) {
        float var = expf(tanhf(logvar[k * DD + t]));
        svar[t]  = var;
        smean[t] = means[k * DD + t];
        red[t]   = logf(var + 1e-8f);
    }
    __syncthreads();

    int w = t >> 6, lane = t & 63;
    const float* trik = tri + (size_t)k * DD * DD;
    __hip_bfloat16* Mk = Mb + (size_t)k * DD * DD;
#pragma unroll
    for (int rr = 0; rr < 8; rr++) {
        int i = slice * 32 + w * 8 + rr;
        int j0 = lane, j1 = lane + 64;
        float m0 = (j0 < i) ? trik[i * DD + j0] * svar[j0] : ((j0 == i) ? svar[j0] : 0.f);
        float m1 = (j1 < i) ? trik[i * DD + j1] * svar[j1] : ((j1 == i) ? svar[j1] : 0.f);
        Mk[i * DD + j0] = __float2bfloat16(m0);
        Mk[i * DD + j1] = __float2bfloat16(m1);
        float b = m0 * smean[j0] + m1 * smean[j1];
#pragma unroll
        for (int off = 32; off; off >>= 1) b += __shfl_xor(b, off, 64);
        if (lane == 0) nbvec[k * DD + i] = -b;
    }

    __syncthreads();
    if (slice == 0 && t < 64) {
        float ld = red[t] + red[t + 64];
#pragma unroll
        for (int off = 32; off; off >>= 1) ld += __shfl_xor(ld, off, 64);
        float w0 = weigh[t], w1 = weigh[t + 64];
        float mx = fmaxf(w0, w1);
#pragma unroll
        for (int off = 32; off; off >>= 1) mx = fmaxf(mx, __shfl_xor(mx, off, 64));
        float e = expf(w0 - mx) + expf(w1 - mx);
#pragma unroll
        for (int off = 32; off; off >>= 1) e += __shfl_xor(e, off, 64);
        if (t == 0) cvec[k] = ld + weigh[k] - (mx + logf(e));
    }
}

// ---------------- gemm_q: 512 thr, 128 n-rows, 8 k's. M split across wave halves.
// Wave w(0..3): n-slice w (32 rows), M-rows 0..63. Wave w+4: same rows, M-rows 64..127.
// M_k staged 32KB into 64KB LDS dbuf (XOR swizzle); nbvec in LDS; q combined via LDS.
__global__ __launch_bounds__(512, 4) void gemm_q(const float* __restrict__ X,
                                                 const __hip_bfloat16* __restrict__ Mb,
                                                 const float* __restrict__ nbvec,
                                                 const float* __restrict__ cvec,
                                                 float* __restrict__ pm,
                                                 float* __restrict__ ps) {
    __shared__ char smem[70656];   // [0,64K) M dbuf | [64K,68K) nb | [68K,+1K) q parts
    float* nb    = (float*)(smem + 65536);
    float* qpart = (float*)(smem + 69632);

    int tid  = threadIdx.x;
    int w    = tid >> 6, lane = tid & 63;
    int quad = lane >> 4, l15 = lane & 15;
    int nslice = w & 3, mhalf = w >> 2;
    int n0 = blockIdx.x * 128;
    int kg = blockIdx.y, k0 = kg * 8;

    // nbvec -> LDS (1024 floats, contiguous)
    nb[tid]       = nbvec[(k0 << 7) + tid];
    nb[tid + 512] = nbvec[(k0 << 7) + 512 + tid];
    float ck[8];
#pragma unroll
    for (int kk = 0; kk < 8; kk++) ck[kk] = cvec[k0 + kk];

    // X fragments (B-operand): Xf[nt][s], row = n0 + nslice*32 + nt*16 + l15
    bf16x8 Xf[2][4];
#pragma unroll
    for (int nt = 0; nt < 2; nt++) {
        const float* xr = X + (size_t)(n0 + nslice * 32 + nt * 16 + l15) * DD;
#pragma unroll
        for (int s = 0; s < 4; s++) {
            const float* p = xr + s * 32 + quad * 8;
            float4 x0 = *(const float4*)(p);
            float4 x1 = *(const float4*)(p + 4);
            bf16x8 a;
            a[0] = f2bf(x0.x); a[1] = f2bf(x0.y); a[2] = f2bf(x0.z); a[3] = f2bf(x0.w);
            a[4] = f2bf(x1.x); a[5] = f2bf(x1.y); a[6] = f2bf(x1.z); a[7] = f2bf(x1.w);
            Xf[nt][s] = a;
        }
    }

    // stage M_{k0+kk} into LDS buffer par (0/1), XOR-swizzled rows; wave w: rows w*16..+15
    int rlo = lane >> 4, cl = lane & 15;
    auto stage = [&](int kk, int parbuf) {
        const char* gk = (const char*)Mb + ((size_t)(k0 + kk) << 15);
#pragma unroll
        for (int i = 0; i < 4; i++) {
            int row = w * 16 + i * 4 + rlo;
            const char* g = gk + row * 256 + ((cl ^ (row & 15)) << 4);
            char* lp = smem + parbuf * 32768 + w * 4096 + i * 1024;
            __builtin_amdgcn_global_load_lds((glb_u32*)g, (lds_u32*)lp, 16, 0, 0);
        }
    };

    stage(0, 0);

    // swizzled A-frag read bases: row = mhalf*64 + mt*16 + l15, chunk (s*4+quad)^l15
    const char* rbs[4];
#pragma unroll
    for (int s = 0; s < 4; s++)
        rbs[s] = smem + (mhalf * 64 + l15) * 256 + (((s * 4 + quad) ^ l15) << 4);

    float rm[2], rsum[2];
#pragma unroll
    for (int nt = 0; nt < 2; nt++) { rm[nt] = -INFINITY; rsum[nt] = 0.f; }

    __syncthreads();   // nb stores + stage(0) drained (vmcnt before barrier)

#pragma unroll 1
    for (int kk = 0; kk < 8; kk++) {
        int par = (kk & 1) * 32768;
        if (kk < 7) stage(kk + 1, (kk + 1) & 1);

        // acc init = -b[m] from LDS (broadcast within quad)
        f32x4 acc[4][2];
#pragma unroll
        for (int mt = 0; mt < 4; mt++) {
            f32x4 b4 = *(const f32x4*)(nb + (kk << 7) + mhalf * 64 + mt * 16 + quad * 4);
            acc[mt][0] = b4;
            acc[mt][1] = b4;
        }

#pragma unroll
        for (int s = 0; s < 4; s++) {
#pragma unroll
            for (int mt = 0; mt < 4; mt++) {
                bf16x8 Af = *(const bf16x8*)(rbs[s] + par + mt * 4096);
#pragma unroll
                for (int nt = 0; nt < 2; nt++)
                    acc[mt][nt] = __builtin_amdgcn_mfma_f32_16x16x32_bf16(Af, Xf[nt][s], acc[mt][nt], 0, 0, 0);
            }
        }

        // partial q over this wave's 64 M-rows
        float qv[2];
#pragma unroll
        for (int nt = 0; nt < 2; nt++) {
            float q = 0.f;
#pragma unroll
            for (int mt = 0; mt < 4; mt++)
#pragma unroll
                for (int r = 0; r < 4; r++) {
                    float z = acc[mt][nt][r];
                    q = fmaf(z, z, q);
                }
            q += __shfl_xor(q, 16, 64);
            q += __shfl_xor(q, 32, 64);
            qv[nt] = q;
        }
        // upper-half waves publish partials (parity-buffered to avoid WAR across kk)
        float* qp = qpart + (kk & 1) * 128;
        if (mhalf == 1 && quad == 0) {
            qp[nslice * 32 + l15]      = qv[0];
            qp[nslice * 32 + 16 + l15] = qv[1];
        }
        __syncthreads();
        if (mhalf == 0) {
#pragma unroll
            for (int nt = 0; nt < 2; nt++) {
                float qtot = qv[nt] + qp[nslice * 32 + nt * 16 + l15];
                float v = fmaf(qtot, -0.5f, ck[kk]);
                float nm = fmaxf(rm[nt], v);
                rsum[nt] = rsum[nt] * __expf(rm[nt] - nm) + __expf(v - nm);
                rm[nt] = nm;
            }
        }
    }

    if (mhalf == 0 && quad == 0) {
#pragma unroll
        for (int nt = 0; nt < 2; nt++) {
            int idx = kg * NN + n0 + nslice * 32 + nt * 16 + l15;
            pm[idx] = rm[nt];
            ps[idx] = rsum[nt];
        }
    }
}

// ---------------- finalize: merge 16 LSE partials per n, mean. 32 blocks x 256.
__global__ __launch_bounds__(256) void finalize(const float* __restrict__ pm,
                                                const float* __restrict__ ps,
                                                float* __restrict__ out) {
    __shared__ float sred[256];
    int t = threadIdx.x;
    int n = blockIdx.x * 256 + t;
    float M = -INFINITY, S = 0.f;
#pragma unroll
    for (int g = 0; g < 16; g++) {
        float m = pm[(size_t)g * NN + n];
        float s = ps[(size_t)g * NN + n];
        float nm = fmaxf(M, m);
        S = S * expf(M - nm) + s * expf(m - nm);
        M = nm;
    }
    float lse = M + logf(S);
    const float logC = -64.f * 1.8378770664093453f;
    sred[t] = (-logC - lse) * (1.f / (float)NN);
    __syncthreads();
    for (int off = 128; off > 0; off >>= 1) { if (t < off) sred[t] += sred[t + off]; __syncthreads(); }
    if (t == 0) atomicAdd(out, sred[0]);
}

extern "C" void kernel_launch(void* const* d_in, const int* in_sizes, int n_in,
                              void* d_out, int out_size, void* d_ws, size_t ws_size,
                              hipStream_t stream) {
    const float* X      = (const float*)d_in[0];
    const float* means  = (const float*)d_in[1];
    const float* logvar = (const float*)d_in[2];
    const float* tri    = (const float*)d_in[3];
    const float* weigh  = (const float*)d_in[4];
    float* out = (float*)d_out;

    char* ws = (char*)d_ws;
    __hip_bfloat16* Mb    = (__hip_bfloat16*)(ws);          // 4 MiB
    float*          nbvec = (float*)(ws + 4194304);         // 64 KiB
    float*          cvec  = (float*)(ws + 4259840);         // 512 B
    float*          pm    = (float*)(ws + 4325376);         // 512 KiB (16 x 8192)
    float*          ps    = (float*)(ws + 4849664);         // 512 KiB

    prep_k<<<dim3(KK, 4), 256, 0, stream>>>(means, logvar, tri, weigh, Mb, nbvec, cvec, out);
    gemm_q<<<dim3(NN / 128, KK / 8), 512, 0, stream>>>(X, Mb, nbvec, cvec, pm, ps);
    finalize<<<NN / 256, 256, 0, stream>>>(pm, ps, out);
}

// Round 6
// 108.870 us; speedup vs baseline: 1.8864x; 1.0820x over previous
//
#include <hip/hip_runtime.h>
#include <hip/hip_bf16.h>
#include <math.h>
#include <stdint.h>

#define NN 8192
#define KK 128
#define DD 128

typedef int   i32x8 __attribute__((ext_vector_type(8)));
typedef float f32x4 __attribute__((ext_vector_type(4)));
typedef __attribute__((address_space(3))) uint32_t lds_u32;
typedef const __attribute__((address_space(1))) uint32_t glb_u32;

// ---------------- prep_k: M_k (fp8 e4m3, row-major bytes), nbvec = -(M_k*mean_k),
// cvec = logdet + logsoftmax(w)_k. grid (KK,4) x 256. Block(0,0) zeroes d_out.
__global__ __launch_bounds__(256) void prep_k(const float* __restrict__ means,
                                              const float* __restrict__ logvar,
                                              const float* __restrict__ tri,
                                              const float* __restrict__ weigh,
                                              uint8_t* __restrict__ M8,
                                              float* __restrict__ nbvec,
                                              float* __restrict__ cvec,
                                              float* __restrict__ out) {
    int k = blockIdx.x, slice = blockIdx.y;
    int t = threadIdx.x;
    if (k == 0 && slice == 0 && t == 0) out[0] = 0.f;
    __shared__ float svar[DD], smean[DD], red[DD];
    if (t < DD) {
        float var = expf(tanhf(logvar[k * DD + t]));
        svar[t]  = var;
        smean[t] = means[k * DD + t];
        red[t]   = logf(var + 1e-8f);
    }
    __syncthreads();

    int w = t >> 6, lane = t & 63;
    const float* trik = tri + (size_t)k * DD * DD;
    uint8_t* Mk8 = M8 + ((size_t)k << 14);   // 16384 bytes per k
#pragma unroll
    for (int rr = 0; rr < 8; rr++) {
        int i = slice * 32 + w * 8 + rr;
        int j0 = lane, j1 = lane + 64;
        float m0 = (j0 < i) ? trik[i * DD + j0] * svar[j0] : ((j0 == i) ? svar[j0] : 0.f);
        float m1 = (j1 < i) ? trik[i * DD + j1] * svar[j1] : ((j1 == i) ? svar[j1] : 0.f);
        int pk = __builtin_amdgcn_cvt_pk_fp8_f32(m0, m1, 0, 0);
        Mk8[i * DD + j0] = (uint8_t)(pk & 0xFF);
        Mk8[i * DD + j1] = (uint8_t)((pk >> 8) & 0xFF);
        float b = m0 * smean[j0] + m1 * smean[j1];
#pragma unroll
        for (int off = 32; off; off >>= 1) b += __shfl_xor(b, off, 64);
        if (lane == 0) nbvec[k * DD + i] = -b;
    }

    __syncthreads();
    if (slice == 0 && t < 64) {
        float ld = red[t] + red[t + 64];
#pragma unroll
        for (int off = 32; off; off >>= 1) ld += __shfl_xor(ld, off, 64);
        float w0 = weigh[t], w1 = weigh[t + 64];
        float mx = fmaxf(w0, w1);
#pragma unroll
        for (int off = 32; off; off >>= 1) mx = fmaxf(mx, __shfl_xor(mx, off, 64));
        float e = expf(w0 - mx) + expf(w1 - mx);
#pragma unroll
        for (int off = 32; off; off >>= 1) e += __shfl_xor(e, off, 64);
        if (t == 0) cvec[k] = ld + weigh[k] - (mx + logf(e));
    }
}

// ---------------- gemm_q: fp8 MX MFMA (16x16x128, unit scales). 256 thr = 4 waves:
// wave = (mhalf = w>>1, ng = w&1). Wave owns 64 n-rows (nt=4) x 64 M-rows (mt=4).
// M_k fp8 (16KB) staged to LDS dbuf via global_load_lds, XOR-swizzled 16B chunks.
// K=128 completes per MFMA -> acc lives per-mt only (16 regs). Fused running-LSE.
__global__ __launch_bounds__(256, 4) void gemm_q(const float* __restrict__ X,
                                                 const uint8_t* __restrict__ M8,
                                                 const float* __restrict__ nbvec,
                                                 const float* __restrict__ cvec,
                                                 float* __restrict__ pm,
                                                 float* __restrict__ ps) {
    __shared__ char smem[38912];   // [0,32K) M dbuf | [32K,36K) nb | [36K,+1K) qpart
    float* nb    = (float*)(smem + 32768);
    float* qpart = (float*)(smem + 36864);

    int tid  = threadIdx.x;
    int w    = tid >> 6, lane = tid & 63;
    int quad = lane >> 4, l15 = lane & 15;
    int ng = w & 1, mhalf = w >> 1;
    int n0 = blockIdx.x * 128;
    int kg = blockIdx.y, k0 = kg * 8;

    // nbvec -> LDS (1024 floats)
    *(float4*)(nb + tid * 4) = *(const float4*)(nbvec + (k0 << 7) + tid * 4);

    // X fragments (B-operand), fp8: lane byte p (reg 4r+b) = X[row][quad*32 + p]
    i32x8 Xf[4];
#pragma unroll
    for (int nt = 0; nt < 4; nt++) {
        const float* xr = X + (size_t)(n0 + ng * 64 + nt * 16 + l15) * DD + quad * 32;
        i32x8 v;
#pragma unroll
        for (int r = 0; r < 8; r++) {
            float4 f = *(const float4*)(xr + r * 4);
            int pk = __builtin_amdgcn_cvt_pk_fp8_f32(f.x, f.y, 0, 0);
            pk     = __builtin_amdgcn_cvt_pk_fp8_f32(f.z, f.w, pk, 1);
            v[r] = pk;
        }
        Xf[nt] = v;
    }

    // stage M_{k0+kk} (16 KB) into LDS buf par: LDS[row][c] = G[row][c ^ (row&7)]
    auto stage = [&](int kk, int par) {
        const uint8_t* gk = M8 + ((size_t)(k0 + kk) << 14);
#pragma unroll
        for (int i = 0; i < 4; i++) {
            int rowbase = w * 32 + i * 8;
            int row = rowbase + (lane >> 3);
            int ch  = (lane & 7) ^ (row & 7);
            __builtin_amdgcn_global_load_lds((glb_u32*)(gk + row * 128 + ch * 16),
                                             (lds_u32*)(smem + par * 16384 + rowbase * 128),
                                             16, 0, 0);
        }
    };

    stage(0, 0);

    float rm[4], rsum[4];
#pragma unroll
    for (int nt = 0; nt < 4; nt++) { rm[nt] = -INFINITY; rsum[nt] = 0.f; }

    __syncthreads();   // nb + stage(0) visible

#pragma unroll 1
    for (int kk = 0; kk < 8; kk++) {
        int par = kk & 1;
        if (kk < 7) stage(kk + 1, par ^ 1);

        float qv[4] = {0.f, 0.f, 0.f, 0.f};
#pragma unroll
        for (int mt = 0; mt < 4; mt++) {
            int row = mhalf * 64 + mt * 16 + l15;
            const char* rb = smem + par * 16384 + row * 128;
            int sw = l15 & 7;
            uint4 lo = *(const uint4*)(rb + (((quad * 2)     ^ sw) << 4));
            uint4 hi = *(const uint4*)(rb + (((quad * 2 + 1) ^ sw) << 4));
            i32x8 Af = {(int)lo.x, (int)lo.y, (int)lo.z, (int)lo.w,
                        (int)hi.x, (int)hi.y, (int)hi.z, (int)hi.w};
            // acc init = -b[m]; K=128 completes in ONE mfma per (mt,nt)
            f32x4 b4 = *(const f32x4*)(nb + (kk << 7) + mhalf * 64 + mt * 16 + quad * 4);
            f32x4 acc[4];
#pragma unroll
            for (int nt = 0; nt < 4; nt++) {
                acc[nt] = __builtin_amdgcn_mfma_scale_f32_16x16x128_f8f6f4(
                    Af, Xf[nt], b4, 0, 0, 0, 0x7F7F7F7F, 0, 0x7F7F7F7F);
            }
#pragma unroll
            for (int nt = 0; nt < 4; nt++)
#pragma unroll
                for (int r = 0; r < 4; r++) {
                    float z = acc[nt][r];
                    qv[nt] = fmaf(z, z, qv[nt]);
                }
        }

        // reduce q across quads (lane bits 4,5)
#pragma unroll
        for (int nt = 0; nt < 4; nt++) {
            qv[nt] += __shfl_xor(qv[nt], 16, 64);
            qv[nt] += __shfl_xor(qv[nt], 32, 64);
        }
        // 2-way M-split combine via parity-buffered LDS strip
        if (mhalf == 1 && quad == 0) {
#pragma unroll
            for (int nt = 0; nt < 4; nt++)
                qpart[par * 128 + ng * 64 + nt * 16 + l15] = qv[nt];
        }
        __syncthreads();
        if (mhalf == 0) {
            float ck = cvec[k0 + kk];
#pragma unroll
            for (int nt = 0; nt < 4; nt++) {
                float qtot = qv[nt] + qpart[par * 128 + ng * 64 + nt * 16 + l15];
                float v = fmaf(qtot, -0.5f, ck);
                float nm = fmaxf(rm[nt], v);
                rsum[nt] = rsum[nt] * __expf(rm[nt] - nm) + __expf(v - nm);
                rm[nt] = nm;
            }
        }
    }

    if (mhalf == 0 && quad == 0) {
#pragma unroll
        for (int nt = 0; nt < 4; nt++) {
            int idx = kg * NN + n0 + ng * 64 + nt * 16 + l15;
            pm[idx] = rm[nt];
            ps[idx] = rsum[nt];
        }
    }
}

// ---------------- finalize: merge 16 LSE partials per n, mean. 32 blocks x 256.
__global__ __launch_bounds__(256) void finalize(const float* __restrict__ pm,
                                                const float* __restrict__ ps,
                                                float* __restrict__ out) {
    __shared__ float sred[256];
    int t = threadIdx.x;
    int n = blockIdx.x * 256 + t;
    float M = -INFINITY, S = 0.f;
#pragma unroll
    for (int g = 0; g < 16; g++) {
        float m = pm[(size_t)g * NN + n];
        float s = ps[(size_t)g * NN + n];
        float nm = fmaxf(M, m);
        S = S * expf(M - nm) + s * expf(m - nm);
        M = nm;
    }
    float lse = M + logf(S);
    const float logC = -64.f * 1.8378770664093453f;
    sred[t] = (-logC - lse) * (1.f / (float)NN);
    __syncthreads();
    for (int off = 128; off > 0; off >>= 1) { if (t < off) sred[t] += sred[t + off]; __syncthreads(); }
    if (t == 0) atomicAdd(out, sred[0]);
}

extern "C" void kernel_launch(void* const* d_in, const int* in_sizes, int n_in,
                              void* d_out, int out_size, void* d_ws, size_t ws_size,
                              hipStream_t stream) {
    const float* X      = (const float*)d_in[0];
    const float* means  = (const float*)d_in[1];
    const float* logvar = (const float*)d_in[2];
    const float* tri    = (const float*)d_in[3];
    const float* weigh  = (const float*)d_in[4];
    float* out = (float*)d_out;

    char* ws = (char*)d_ws;
    uint8_t* M8    = (uint8_t*)(ws);                 // 2 MiB
    float*   nbvec = (float*)(ws + 2097152);         // 64 KiB
    float*   cvec  = (float*)(ws + 2162688);         // 2 KiB pad
    float*   pm    = (float*)(ws + 2164736);         // 512 KiB (16 x 8192)
    float*   ps    = (float*)(ws + 2689024);         // 512 KiB

    prep_k<<<dim3(KK, 4), 256, 0, stream>>>(means, logvar, tri, weigh, M8, nbvec, cvec, out);
    gemm_q<<<dim3(NN / 128, KK / 8), 256, 0, stream>>>(X, M8, nbvec, cvec, pm, ps);
    finalize<<<NN / 256, 256, 0, stream>>>(pm, ps, out);
}